// Round 9
// baseline (147.461 us; speedup 1.0000x reference)
//
#include <hip/hip_runtime.h>
#include <hip/hip_bf16.h>

#define CC 128
#define NSP 16384              // 128*128 spatial
#define NFULL (CC * NSP)

typedef float f32x4 __attribute__((ext_vector_type(4)));
typedef short s16x8 __attribute__((ext_vector_type(8)));
typedef unsigned int u32x4 __attribute__((ext_vector_type(4)));

__device__ __forceinline__ unsigned bf16rne(float f) {
  unsigned u = __float_as_uint(f);
  return ((u + 0x7FFFu + ((u >> 16) & 1u)) >> 16) & 0xFFFFu;
}

// RNE hi/lo split of a float pair -> packed {hi, lo} u32 (bf16x2 each)
__device__ __forceinline__ uint2 packpair(float x0, float x1) {
  __hip_bfloat162 h2 = __float22bfloat162_rn(make_float2(x0, x1));
  unsigned hu = *reinterpret_cast<unsigned*>(&h2);   // lo16=bf16(x0), hi16=bf16(x1)
  float hf0 = __uint_as_float(hu << 16);
  float hf1 = __uint_as_float(hu & 0xFFFF0000u);
  __hip_bfloat162 l2 = __float22bfloat162_rn(make_float2(x0 - hf0, x1 - hf1));
  unsigned lu = *reinterpret_cast<unsigned*>(&l2);
  return make_uint2(hu, lu);
}

// zero M/rs/rt (mode-1 fallback only)
__global__ __launch_bounds__(256) void zerok(float* __restrict__ p, int n) {
  int i = blockIdx.x * 256 + threadIdx.x;
  if (i < n) p[i] = 0.f;
}

// ---------------------------------------------------------------------------
// K1 (MFMA, LDS-staged, 8 waves): per (chunk,b): partial Xt*Xs^T over 64-n
// stages. 512 threads stage 128 rows x 64 n of Xt and Xs hi/lo bf16 (each
// element converted once); 8 waves (2x4) each compute a 64x32 tile via 48
// MFMA per stage. Row sums fold into staging.
// ---------------------------------------------------------------------------
__global__ __launch_bounds__(512, 4) void k1_mfma(const float* __restrict__ x,
    float* __restrict__ Mdst, float* __restrict__ rs, float* __restrict__ rt,
    float* __restrict__ rspart, float* __restrict__ rtpart,
    int nst, int mode) {
  const int b = blockIdx.y;
  const int chunk = blockIdx.x;
  const int n0 = chunk * (nst * 64);
  const int t = threadIdx.x;
  const int w = t >> 6, l = t & 63;
  const int wr = w >> 2, wc = w & 3;   // 2x4 wave grid: 64-row x 32-col tiles
  const int lr = l & 15, lg = l >> 4;
  const int r0 = t >> 2;               // staging row 0..127
  const int q = t & 3;                 // staging n-quarter (16 floats)
  __shared__ unsigned short Ahi[128 * 64];   // 16KB each, swz: byte^((row&7)<<4)
  __shared__ unsigned short Alo[128 * 64];
  __shared__ unsigned short Bhi[128 * 64];
  __shared__ unsigned short Blo[128 * 64];
  const float* Xs = x + (size_t)b * NFULL;
  const float* Xt = x + (size_t)(b + 8) * NFULL;

  f32x4 acc[4][2];
#pragma unroll
  for (int a = 0; a < 4; ++a)
#pragma unroll
    for (int bb = 0; bb < 2; ++bb) acc[a][bb] = (f32x4){0.f, 0.f, 0.f, 0.f};
  float rtp = 0.f, rsp = 0.f;

  for (int s = 0; s < nst; ++s) {
    const int nb = n0 + s * 64;
    __syncthreads();                   // prev-stage reads done before overwrite
    {
      const float* At = Xt + (size_t)r0 * NSP + nb + q * 16;
      const float* Bs = Xs + (size_t)r0 * NSP + nb + q * 16;
      f32x4 av[4], bv[4];
#pragma unroll
      for (int i = 0; i < 4; ++i) av[i] = *(const f32x4*)(At + i * 4);
#pragma unroll
      for (int i = 0; i < 4; ++i) bv[i] = *(const f32x4*)(Bs + i * 4);
#pragma unroll
      for (int i = 0; i < 4; ++i) {
        rtp += (av[i][0] + av[i][1]) + (av[i][2] + av[i][3]);
        rsp += (bv[i][0] + bv[i][1]) + (bv[i][2] + bv[i][3]);
      }
      u32x4 h0, l0, h1, l1;
#pragma unroll
      for (int i = 0; i < 2; ++i) {
        uint2 r1 = packpair(av[i][0], av[i][1]);
        h0[2 * i] = r1.x; l0[2 * i] = r1.y;
        uint2 r2 = packpair(av[i][2], av[i][3]);
        h0[2 * i + 1] = r2.x; l0[2 * i + 1] = r2.y;
        uint2 r3 = packpair(av[2 + i][0], av[2 + i][1]);
        h1[2 * i] = r3.x; l1[2 * i] = r3.y;
        uint2 r4 = packpair(av[2 + i][2], av[2 + i][3]);
        h1[2 * i + 1] = r4.x; l1[2 * i + 1] = r4.y;
      }
      {
        int base = r0 * 128 + q * 32;
        int sw = (r0 & 7) << 4;
        *(u32x4*)((char*)Ahi + ((base) ^ sw)) = h0;
        *(u32x4*)((char*)Ahi + ((base + 16) ^ sw)) = h1;
        *(u32x4*)((char*)Alo + ((base) ^ sw)) = l0;
        *(u32x4*)((char*)Alo + ((base + 16) ^ sw)) = l1;
      }
#pragma unroll
      for (int i = 0; i < 2; ++i) {
        uint2 r1 = packpair(bv[i][0], bv[i][1]);
        h0[2 * i] = r1.x; l0[2 * i] = r1.y;
        uint2 r2 = packpair(bv[i][2], bv[i][3]);
        h0[2 * i + 1] = r2.x; l0[2 * i + 1] = r2.y;
        uint2 r3 = packpair(bv[2 + i][0], bv[2 + i][1]);
        h1[2 * i] = r3.x; l1[2 * i] = r3.y;
        uint2 r4 = packpair(bv[2 + i][2], bv[2 + i][3]);
        h1[2 * i + 1] = r4.x; l1[2 * i + 1] = r4.y;
      }
      {
        int base = r0 * 128 + q * 32;
        int sw = (r0 & 7) << 4;
        *(u32x4*)((char*)Bhi + ((base) ^ sw)) = h0;
        *(u32x4*)((char*)Bhi + ((base + 16) ^ sw)) = h1;
        *(u32x4*)((char*)Blo + ((base) ^ sw)) = l0;
        *(u32x4*)((char*)Blo + ((base + 16) ^ sw)) = l1;
      }
    }
    __syncthreads();
#pragma unroll
    for (int kk = 0; kk < 2; ++kk) {
      s16x8 ah[4], al[4], bh[2], bl[2];
#pragma unroll
      for (int a = 0; a < 4; ++a) {
        int row = wr * 64 + a * 16 + lr;
        int off = (row * 128 + kk * 64 + lg * 16) ^ ((row & 7) << 4);
        ah[a] = *(const s16x8*)((char*)Ahi + off);
        al[a] = *(const s16x8*)((char*)Alo + off);
      }
#pragma unroll
      for (int bb = 0; bb < 2; ++bb) {
        int row = wc * 32 + bb * 16 + lr;
        int off = (row * 128 + kk * 64 + lg * 16) ^ ((row & 7) << 4);
        bh[bb] = *(const s16x8*)((char*)Bhi + off);
        bl[bb] = *(const s16x8*)((char*)Blo + off);
      }
#pragma unroll
      for (int a = 0; a < 4; ++a)
#pragma unroll
        for (int bb = 0; bb < 2; ++bb) {
          acc[a][bb] = __builtin_amdgcn_mfma_f32_16x16x32_bf16(ah[a], bh[bb], acc[a][bb], 0, 0, 0);
          acc[a][bb] = __builtin_amdgcn_mfma_f32_16x16x32_bf16(ah[a], bl[bb], acc[a][bb], 0, 0, 0);
          acc[a][bb] = __builtin_amdgcn_mfma_f32_16x16x32_bf16(al[a], bh[bb], acc[a][bb], 0, 0, 0);
        }
    }
  }

  // row-sum reduce over the 4 n-quarters (q = lane&3)
  {
    float vt = rtp;
    vt += __shfl_xor(vt, 1);
    vt += __shfl_xor(vt, 2);
    float vs = rsp;
    vs += __shfl_xor(vs, 1);
    vs += __shfl_xor(vs, 2);
    if (q == 0) {
      if (mode == 0) {
        rtpart[((size_t)chunk * 8 + b) * CC + r0] = vt;
        rspart[((size_t)chunk * 8 + b) * CC + r0] = vs;
      } else {
        atomicAdd(&rt[b * CC + r0], vt);
        atomicAdd(&rs[b * CC + r0], vs);
      }
    }
  }

  const int rquad = lg << 2;
  if (mode == 0) {
    float* Mp = Mdst + ((size_t)chunk * 8 + b) * (CC * CC);
#pragma unroll
    for (int a = 0; a < 4; ++a)
#pragma unroll
      for (int bb = 0; bb < 2; ++bb)
#pragma unroll
        for (int r = 0; r < 4; ++r) {
          int i = wr * 64 + a * 16 + rquad + r;
          int j = wc * 32 + bb * 16 + lr;
          Mp[i * CC + j] = acc[a][bb][r];
        }
  } else {
    float* Mp = Mdst + (size_t)b * (CC * CC);
#pragma unroll
    for (int a = 0; a < 4; ++a)
#pragma unroll
      for (int bb = 0; bb < 2; ++bb)
#pragma unroll
        for (int r = 0; r < 4; ++r) {
          int i = wr * 64 + a * 16 + rquad + r;
          int j = wc * 32 + bb * 16 + lr;
          atomicAdd(&Mp[i * CC + j], acc[a][bb][r]);
        }
  }
}

// Sum partials, vectorized. Blocks [0,128): M. Block 128: rt. Block 129: rs.
__global__ __launch_bounds__(256) void k1_reduce(const float* __restrict__ Mpart,
    const float* __restrict__ rspart, const float* __restrict__ rtpart,
    float* __restrict__ M, float* __restrict__ rs, float* __restrict__ rt,
    int NB) {
  const int t = threadIdx.x;
  if (blockIdx.x < 128) {
    const int i4 = blockIdx.x * 256 + t;     // < 32768
    const int b = i4 >> 12;
    const int e = (i4 & 4095) * 4;
    f32x4 s = (f32x4){0.f, 0.f, 0.f, 0.f};
    for (int c = 0; c < NB; ++c) {
      f32x4 v = *(const f32x4*)(Mpart + ((size_t)c * 8 + b) * (CC * CC) + e);
      s += v;
    }
    *(f32x4*)(M + (size_t)b * CC * CC + e) = s;
  } else if (blockIdx.x == 128) {
    const int e = t * 4;                      // < 1024
    f32x4 s = (f32x4){0.f, 0.f, 0.f, 0.f};
    for (int c = 0; c < NB; ++c) s += *(const f32x4*)(rtpart + (size_t)c * 1024 + e);
    *(f32x4*)(rt + e) = s;
  } else {
    const int e = t * 4;
    f32x4 s = (f32x4){0.f, 0.f, 0.f, 0.f};
    for (int c = 0; c < NB; ++c) s += *(const f32x4*)(rspart + (size_t)c * 1024 + e);
    *(f32x4*)(rs + e) = s;
  }
}

// ---------------------------------------------------------------------------
// K2ab fused: T1=Wq*M, T2=Wq*M^T, us/ut, G + softmax (st & ts).
// grid (16 c-groups of 8 rows, 8 b). Cols strided: lane L owns {L+32j}.
// ---------------------------------------------------------------------------
__global__ __launch_bounds__(256) void k2ab(const float* __restrict__ M,
    const float* __restrict__ qw, const float* __restrict__ kw,
    const float* __restrict__ qb, const float* __restrict__ kb,
    const float* __restrict__ rs, const float* __restrict__ rt,
    float* __restrict__ Ast, float* __restrict__ Ats) {
  const int b = blockIdx.y;
  const int c0 = blockIdx.x * 8;
  __shared__ float Big[128][132];      // M, later Wk (132: 16B-aligned rows)
  __shared__ float Wq[8][128];
  __shared__ float T12[2][8][128];
  __shared__ float uvv[2][8];
  __shared__ float wv2[2][128];
  const int t = threadIdx.x;
  const float* Mb = M + (size_t)b * CC * CC;
#pragma unroll
  for (int p = 0; p < 16; ++p) {
    int f = p * 256 + t;
    int row = f >> 5, c4 = (f & 31) * 4;
    *(f32x4*)&Big[row][c4] = *(const f32x4*)(Mb + row * CC + c4);
  }
  { int row = t >> 5, c4 = (t & 31) * 4;
    *(f32x4*)&Wq[row][c4] = *(const f32x4*)(qw + (c0 + row) * CC + c4); }
  __syncthreads();
  if (t < 16) {
    int c = t & 7;
    const float* r = ((t < 8) ? rs : rt) + b * CC;
    float s = 0.f;
    for (int i = 0; i < CC; ++i) s += Wq[c][i] * r[i];
    uvv[(t < 8) ? 1 : 0][c] = s;       // us->[1], ut->[0]
  }
  const int tr = t >> 5;               // row 0..7
  const int L = t & 31;                // col lane
  {
    float a1[4] = {0.f, 0.f, 0.f, 0.f}, a2[4] = {0.f, 0.f, 0.f, 0.f};
    for (int i = 0; i < CC; ++i) {
      float wq = Wq[tr][i];
#pragma unroll
      for (int j = 0; j < 4; ++j) a1[j] += wq * Big[i][L + 32 * j];
    }
    for (int i4 = 0; i4 < 32; ++i4) {
      f32x4 wq4 = *(const f32x4*)&Wq[tr][i4 * 4];
#pragma unroll
      for (int j = 0; j < 4; ++j) {
        f32x4 m4 = *(const f32x4*)&Big[L + 32 * j][i4 * 4];
        a2[j] += wq4[0]*m4[0] + wq4[1]*m4[1] + wq4[2]*m4[2] + wq4[3]*m4[3];
      }
    }
#pragma unroll
    for (int j = 0; j < 4; ++j) {
      T12[0][tr][L + 32 * j] = a1[j];
      T12[1][tr][L + 32 * j] = a2[j];
    }
  }
  __syncthreads();
  // overwrite Big with Wk
#pragma unroll
  for (int p = 0; p < 16; ++p) {
    int f = p * 256 + t;
    int row = f >> 5, c4 = (f & 31) * 4;
    *(f32x4*)&Big[row][c4] = *(const f32x4*)(kw + row * CC + c4);
  }
  __syncthreads();
  {
    int d = t & 127, wh = t >> 7;      // 0: rs, 1: rt
    const float* r = (wh ? rt : rs) + b * CC;
    float s = 0.f;
    for (int i4 = 0; i4 < 32; ++i4) {
      f32x4 w4 = *(const f32x4*)&Big[d][i4 * 4];
      s += w4[0]*r[i4*4] + w4[1]*r[i4*4+1] + w4[2]*r[i4*4+2] + w4[3]*r[i4*4+3];
    }
    wv2[wh][d] = s;
  }
  __syncthreads();
  const int c = c0 + tr;
  const float bqc = qb[c];
#pragma unroll 1
  for (int which = 0; which < 2; ++which) {
    float g[4];
#pragma unroll
    for (int j = 0; j < 4; ++j) {
      int d = L + 32 * j;
      g[j] = uvv[which][tr] * kb[d] + bqc * wv2[which][d] + 16384.f * bqc * kb[d];
    }
    for (int j4 = 0; j4 < 32; ++j4) {
      f32x4 tv4 = *(const f32x4*)&T12[which][tr][j4 * 4];
#pragma unroll
      for (int j = 0; j < 4; ++j) {
        f32x4 w4 = *(const f32x4*)&Big[L + 32 * j][j4 * 4];
        g[j] += tv4[0]*w4[0] + tv4[1]*w4[1] + tv4[2]*w4[2] + tv4[3]*w4[3];
      }
    }
    float m = fmaxf(fmaxf(g[0], g[1]), fmaxf(g[2], g[3]));
#pragma unroll
    for (int off = 1; off < 32; off <<= 1) m = fmaxf(m, __shfl_xor(m, off));
    float s = 0.f;
#pragma unroll
    for (int j = 0; j < 4; ++j) { g[j] = expf(g[j] - m); s += g[j]; }
#pragma unroll
    for (int off = 1; off < 32; off <<= 1) s += __shfl_xor(s, off);
    const float inv = 1.f / s;
    float* A = (which ? Ats : Ast) + (size_t)b * CC * CC + (size_t)c * CC;
#pragma unroll
    for (int j = 0; j < 4; ++j) A[L + 32 * j] = g[j] * inv;
  }
}

// ---------------------------------------------------------------------------
// K2cd fused: L = Ast*Ats^T, softmax -> Att, P' = Att*Wv + I (bf16), c0.
// grid (16 c-groups of 8 rows, 8 b).
// ---------------------------------------------------------------------------
__global__ __launch_bounds__(256) void k2cd(const float* __restrict__ Ast,
    const float* __restrict__ Ats, const float* __restrict__ vw,
    const float* __restrict__ vb, unsigned short* __restrict__ Pbf,
    float* __restrict__ c0v) {
  const int b = blockIdx.y;
  const int c0 = blockIdx.x * 8;
  __shared__ float Big[128][132];      // Ats, later Wv[d][i]
  __shared__ float Tl[8][128];
  __shared__ float Al[8][128];
  const int t = threadIdx.x;
  const float* Bb = Ats + (size_t)b * CC * CC;
  const float* Tb = Ast + (size_t)b * CC * CC;
#pragma unroll
  for (int p = 0; p < 16; ++p) {
    int f = p * 256 + t;
    int row = f >> 5, c4 = (f & 31) * 4;
    *(f32x4*)&Big[row][c4] = *(const f32x4*)(Bb + row * CC + c4);
  }
  { int row = t >> 5, c4 = (t & 31) * 4;
    *(f32x4*)&Tl[row][c4] = *(const f32x4*)(Tb + (c0 + row) * CC + c4); }
  __syncthreads();
  const int tr = t >> 5;
  const int L = t & 31;
  {
    float g[4] = {0.f, 0.f, 0.f, 0.f};
    for (int e4 = 0; e4 < 32; ++e4) {
      f32x4 tv4 = *(const f32x4*)&Tl[tr][e4 * 4];
#pragma unroll
      for (int j = 0; j < 4; ++j) {
        f32x4 a4 = *(const f32x4*)&Big[L + 32 * j][e4 * 4];
        g[j] += tv4[0]*a4[0] + tv4[1]*a4[1] + tv4[2]*a4[2] + tv4[3]*a4[3];
      }
    }
    float m = fmaxf(fmaxf(g[0], g[1]), fmaxf(g[2], g[3]));
#pragma unroll
    for (int off = 1; off < 32; off <<= 1) m = fmaxf(m, __shfl_xor(m, off));
    float s = 0.f;
#pragma unroll
    for (int j = 0; j < 4; ++j) { g[j] = expf(g[j] - m); s += g[j]; }
#pragma unroll
    for (int off = 1; off < 32; off <<= 1) s += __shfl_xor(s, off);
    const float inv = 1.f / s;
#pragma unroll
    for (int j = 0; j < 4; ++j) Al[tr][L + 32 * j] = g[j] * inv;
  }
  __syncthreads();
  // overwrite Big with Wv[d][i]
#pragma unroll
  for (int p = 0; p < 16; ++p) {
    int f = p * 256 + t;
    int row = f >> 5, c4 = (f & 31) * 4;
    *(f32x4*)&Big[row][c4] = *(const f32x4*)(vw + row * CC + c4);
  }
  __syncthreads();
  float p4[4] = {0.f, 0.f, 0.f, 0.f};
  for (int d = 0; d < CC; ++d) {
    float av = Al[tr][d];
#pragma unroll
    for (int j = 0; j < 4; ++j) p4[j] += av * Big[d][L + 32 * j];
  }
  float csum = 0.f;
#pragma unroll
  for (int j = 0; j < 4; ++j) csum += Al[tr][L + 32 * j] * vb[L + 32 * j];
#pragma unroll
  for (int off = 1; off < 32; off <<= 1) csum += __shfl_xor(csum, off);
  const int c = c0 + tr;
  if ((c & 31) == L) p4[c >> 5] += 1.0f;      // P' = P + I (residual folded in)
  unsigned short* Pp = Pbf + (size_t)b * CC * CC + (size_t)c * CC;
#pragma unroll
  for (int j = 0; j < 4; ++j) Pp[L + 32 * j] = (unsigned short)bf16rne(p4[j]);
  if (L == 0) c0v[b * CC + c] = csum;
}

// ---------------------------------------------------------------------------
// K3 (MFMA): out[c][n] = sum_e P'[c][e]*x[e][n] + c0[c]  (identity in P').
// 256-n tile per block staged ONCE to LDS (transposed bf16, swizzled);
// P' fragments hoisted to registers per c-half and reused across 4 subtiles.
// Output via nontemporal stores. grid (64 n-tiles, 16 images), 4 waves.
// ---------------------------------------------------------------------------
__global__ __launch_bounds__(256, 2) void k3_mfma(const float* __restrict__ x,
    const unsigned short* __restrict__ Pbf, const float* __restrict__ c0v,
    float* __restrict__ out) {
  const int im = blockIdx.y;
  const int pb = im & 7;
  const int n0 = blockIdx.x * 256;
  const float* X = x + (size_t)im * NFULL;
  float* O = out + (size_t)im * NFULL;
  __shared__ unsigned short XT[256 * 128];   // swizzled: byte ^ (((n>>2)&15)<<4)
  __shared__ float c0l[128];
  const int t = threadIdx.x;
  if (t < 128) c0l[t] = c0v[pb * CC + t];
#pragma unroll
  for (int p = 0; p < 16; ++p) {
    int d0 = 2 * (t >> 4) + 32 * (p & 3);
    int n4 = (t & 15) * 4 + 64 * (p >> 2);
    f32x4 x0 = *(const f32x4*)(X + (size_t)d0 * NSP + n0 + n4);
    f32x4 x1 = *(const f32x4*)(X + (size_t)(d0 + 1) * NSP + n0 + n4);
#pragma unroll
    for (int i = 0; i < 4; ++i) {
      int n = n4 + i;
      __hip_bfloat162 h2 = __float22bfloat162_rn(make_float2(x0[i], x1[i]));
      unsigned pk = *reinterpret_cast<unsigned*>(&h2);
      int off = (n * 256 + d0 * 2) ^ (((n >> 2) & 15) << 4);
      *(unsigned*)((char*)XT + off) = pk;
    }
  }
  __syncthreads();

  const int w = t >> 6, l = t & 63;
  const int ln = l & 15, lg = l >> 4;
#pragma unroll
  for (int h = 0; h < 2; ++h) {
    const unsigned short* Pg = Pbf + (size_t)pb * (CC * CC)
                             + (size_t)(h * 64 + ln) * CC + lg * 8;
    s16x8 Af[4][4];
#pragma unroll
    for (int a = 0; a < 4; ++a)
#pragma unroll
      for (int kk = 0; kk < 4; ++kk)
        Af[a][kk] = *(const s16x8*)(Pg + a * 16 * CC + kk * 32);
#pragma unroll
    for (int sub = 0; sub < 4; ++sub) {
      int row = sub * 64 + w * 16 + ln;
      int sw = ((row >> 2) & 15) << 4;
      s16x8 bf[4];
#pragma unroll
      for (int kk = 0; kk < 4; ++kk)
        bf[kk] = *(const s16x8*)((char*)XT + ((row * 256 + kk * 64 + lg * 16) ^ sw));
      f32x4 acc[4];
#pragma unroll
      for (int a = 0; a < 4; ++a) acc[a] = (f32x4){0.f, 0.f, 0.f, 0.f};
#pragma unroll
      for (int kk = 0; kk < 4; ++kk)
#pragma unroll
        for (int a = 0; a < 4; ++a)
          acc[a] = __builtin_amdgcn_mfma_f32_16x16x32_bf16(Af[a][kk], bf[kk], acc[a], 0, 0, 0);
      int n = n0 + sub * 64 + w * 16 + ln;
#pragma unroll
      for (int a = 0; a < 4; ++a)
#pragma unroll
        for (int r = 0; r < 4; ++r) {
          int c = h * 64 + a * 16 + lg * 4 + r;
          __builtin_nontemporal_store(acc[a][r] + c0l[c], O + (size_t)c * NSP + n);
        }
    }
  }
}

// ---------------------------------------------------------------------------
extern "C" void kernel_launch(void* const* d_in, const int* in_sizes, int n_in,
                              void* d_out, int out_size, void* d_ws, size_t ws_size,
                              hipStream_t stream) {
  (void)in_sizes; (void)n_in; (void)out_size;
  const float* x  = (const float*)d_in[0];
  const float* qw = (const float*)d_in[1];
  const float* qb = (const float*)d_in[2];
  const float* kw = (const float*)d_in[3];
  const float* kb = (const float*)d_in[4];
  const float* vw = (const float*)d_in[5];
  const float* vb = (const float*)d_in[6];
  float* out = (float*)d_out;
  float* ws = (float*)d_ws;
  float* M   = ws;                       // 8*128*128  (M, rs, rt contiguous)
  float* rs  = M + 131072;               // 8*128
  float* rt  = rs + 1024;
  float* AST = rt + 1024;                // 8*128*128
  float* ATS = AST + 131072;
  unsigned short* Pbf = (unsigned short*)(ATS + 131072);  // 8*128*128 bf16
  float* c0v = ATS + 131072 + 65536;
  float* Mpart = c0v + 1024;
  const size_t base_floats = (size_t)(Mpart - ws);

  int NB, mode;
  if (ws_size >= (base_floats + (size_t)64 * (131072 + 2048)) * 4) { NB = 64; mode = 0; }
  else if (ws_size >= (base_floats + (size_t)32 * (131072 + 2048)) * 4) { NB = 32; mode = 0; }
  else { NB = 32; mode = 1; }
  const int nst = (16384 / NB) / 64;     // 64-n stages per chunk
  float* rtpart = Mpart + (size_t)NB * 131072;   // NB*8*128
  float* rspart = rtpart + (size_t)NB * 1024;    // NB*8*128

  if (mode == 1) zerok<<<(133120 + 255) / 256, 256, 0, stream>>>(M, 133120);
  k1_mfma<<<dim3(NB, 8), 512, 0, stream>>>(x, mode ? M : Mpart, rs, rt,
                                           rspart, rtpart, nst, mode);
  if (mode == 0)
    k1_reduce<<<130, 256, 0, stream>>>(Mpart, rspart, rtpart, M, rs, rt, NB);
  k2ab<<<dim3(16, 8), 256, 0, stream>>>(M, qw, kw, qb, kb, rs, rt, AST, ATS);
  k2cd<<<dim3(16, 8), 256, 0, stream>>>(AST, ATS, vw, vb, Pbf, c0v);
  k3_mfma<<<dim3(64, 16), 256, 0, stream>>>(x, Pbf, c0v, out);
}